// Round 12
// baseline (861.072 us; speedup 1.0000x reference)
//
#include <hip/hip_runtime.h>
#include <math.h>

constexpr int NN = 50000;
constexpr int NE = 600000;
constexpr int NG = 256;
constexpr int SB = (NN + 255) / 256;  // scan blocks = 196
constexpr float kBnEps = 1e-5f;
constexpr float kSlope = 0.2f;

__device__ __forceinline__ float rdlane(float v, int l) {
    return __builtin_bit_cast(float, __builtin_amdgcn_readlane(__builtin_bit_cast(int, v), l));
}

// DPP-based add: v += v[permuted lane] — VALU only, no LDS pipe.
template <int CTRL>
__device__ __forceinline__ float dppadd(float v) {
    int t = __builtin_amdgcn_mov_dpp(__builtin_bit_cast(int, v), CTRL, 0xF, 0xF, true);
    return v + __builtin_bit_cast(float, t);
}
// sum over each 16-lane group (all 16 lanes end with the group sum)
__device__ __forceinline__ float sum16(float v) {
    v = dppadd<0xB1>(v);    // quad_perm [1,0,3,2]
    v = dppadd<0x4E>(v);    // quad_perm [2,3,0,1]
    v = dppadd<0x141>(v);   // row_half_mirror
    v = dppadd<0x140>(v);   // row_mirror
    return v;
}

__device__ __forceinline__ float4 fma4(float a, float4 b, float4 c) {
    c.x = fmaf(a, b.x, c.x); c.y = fmaf(a, b.y, c.y);
    c.z = fmaf(a, b.z, c.z); c.w = fmaf(a, b.w, c.w);
    return c;
}

// ---------------- counting sort of edges by dst ----------------
__global__ __launch_bounds__(256) void k_hist(const int* __restrict__ dst, int* __restrict__ cnt)
{
    int e = blockIdx.x * 256 + threadIdx.x;
    if (e < NE) atomicAdd(&cnt[dst[e]], 1);
}

// parallel scan, 3 kernels: per-block inclusive scan, block-sum scan, fixup
__global__ __launch_bounds__(256) void k_scanA(const int* __restrict__ cnt,
                                               int* __restrict__ offs, int* __restrict__ bsum)
{
    __shared__ int s[256];
    int tid = threadIdx.x;
    int i = blockIdx.x * 256 + tid;
    int v = (i < NN) ? cnt[i] : 0;
    s[tid] = v;
    __syncthreads();
    #pragma unroll
    for (int d = 1; d < 256; d <<= 1) {
        int u = (tid >= d) ? s[tid - d] : 0;
        __syncthreads();
        s[tid] += u;
        __syncthreads();
    }
    if (i < NN) offs[i] = s[tid];           // block-local inclusive
    if (tid == 255) bsum[blockIdx.x] = s[255];
}

__global__ __launch_bounds__(256) void k_scanB(int* __restrict__ bsum)
{
    __shared__ int s[256];
    int t = threadIdx.x;
    int v = (t < SB) ? bsum[t] : 0;
    s[t] = v;
    __syncthreads();
    #pragma unroll
    for (int d = 1; d < 256; d <<= 1) {
        int u = (t >= d) ? s[t - d] : 0;
        __syncthreads();
        s[t] += u;
        __syncthreads();
    }
    if (t < SB) bsum[t] = s[t];             // inclusive over block sums
}

__global__ __launch_bounds__(256) void k_scanC(const int* __restrict__ cnt,
                                               const int* __restrict__ bsum,
                                               int* __restrict__ offs, int* __restrict__ cur)
{
    int i = blockIdx.x * 256 + threadIdx.x;
    if (i > NN) return;
    if (i == NN) { offs[NN] = NE; return; }
    int pre = (blockIdx.x > 0) ? bsum[blockIdx.x - 1] : 0;
    int v = offs[i] - cnt[i] + pre;         // global exclusive
    offs[i] = v;
    cur[i] = v;
}

// scatter edges into dst-sorted order; also reorder edge_attr rows (eas)
__global__ __launch_bounds__(256) void k_scatter(const int* __restrict__ dst,
                                                 const int* __restrict__ src,
                                                 const float* __restrict__ ea,
                                                 int* __restrict__ cur,
                                                 int* __restrict__ srcs,
                                                 float* __restrict__ eas)
{
    int e = blockIdx.x * 256 + threadIdx.x;
    if (e < NE) {
        int p = atomicAdd(&cur[dst[e]], 1);
        srcs[p] = src[e];
        const float4* s4 = (const float4*)(ea + (size_t)e * 16);
        float4* d4 = (float4*)(eas + (size_t)p * 16);
        d4[0] = s4[0]; d4[1] = s4[1]; d4[2] = s4[2]; d4[3] = s4[3];
    }
}

// ---------------- fused layer-0: h0 = relu(x@Win+bin) in regs, then dual GEMM ------
// 32 rows/block (8/wave). h0 NEVER touches memory: prologue computes the wave's
// 8 rows into registers (lane = channel), main loop broadcasts via rdlane.
// No LDS, no barriers (spill rule). Main loop: 2 W-loads + 8 rdlane + 64 FMA per k.
__global__ __launch_bounds__(256) void k_lin0(
    const float* __restrict__ x, const float* __restrict__ Win,
    const float* __restrict__ bin, const float* __restrict__ WL,
    const float* __restrict__ WR, const float* __restrict__ bl,
    const float* __restrict__ br, float* __restrict__ outl,
    float* __restrict__ outr)
{
    int tid = threadIdx.x;
    int lane = tid & 63, wave = tid >> 6;
    int row0 = blockIdx.x * 32 + wave * 8;

    // prologue: h0 for 8 rows, lane = channel
    float xreg[8];
    #pragma unroll
    for (int j = 0; j < 8; ++j) {
        int row = row0 + j; if (row >= NN) row = NN - 1;
        xreg[j] = x[(size_t)row * 64 + lane];
    }
    float h0r[8];
    float b0 = bin[lane];
    #pragma unroll
    for (int j = 0; j < 8; ++j) h0r[j] = b0;
    for (int k = 0; k < 64; ++k) {
        float w = Win[k * 64 + lane];
        #pragma unroll
        for (int j = 0; j < 8; ++j) h0r[j] = fmaf(rdlane(xreg[j], k), w, h0r[j]);
    }
    #pragma unroll
    for (int j = 0; j < 8; ++j) h0r[j] = fmaxf(h0r[j], 0.f);

    // dual GEMM K=64, h broadcast straight from registers
    float4 accL[8], accR[8];
    #pragma unroll
    for (int j = 0; j < 8; ++j) {
        accL[j] = make_float4(0.f, 0.f, 0.f, 0.f);
        accR[j] = make_float4(0.f, 0.f, 0.f, 0.f);
    }
    for (int k = 0; k < 64; ++k) {
        float4 wl4 = ((const float4*)(WL + (size_t)k * 256))[lane];
        float4 wr4 = ((const float4*)(WR + (size_t)k * 256))[lane];
        #pragma unroll
        for (int j = 0; j < 8; ++j) {
            float hb = rdlane(h0r[j], k);
            accL[j] = fma4(hb, wl4, accL[j]);
            accR[j] = fma4(hb, wr4, accR[j]);
        }
    }
    float4 bl4 = ((const float4*)bl)[lane];
    float4 br4 = ((const float4*)br)[lane];
    #pragma unroll
    for (int j = 0; j < 8; ++j) {
        int row = row0 + j;
        if (row < NN) {
            float4 o;
            o.x = accL[j].x + bl4.x; o.y = accL[j].y + bl4.y;
            o.z = accL[j].z + bl4.z; o.w = accL[j].w + bl4.w;
            ((float4*)(outl + (size_t)row * 256))[lane] = o;
            float4 pp;
            pp.x = accR[j].x + br4.x; pp.y = accR[j].y + br4.y;
            pp.z = accR[j].z + br4.z; pp.w = accR[j].w + br4.w;
            ((float4*)(outr + (size_t)row * 256))[lane] = pp;
        }
    }
}

// ---------------- dual linear K=256 with BN-folded input and h-prefetch -----------
// r9 shape (32 rows/block, 8/wave, no LDS/barriers, W direct from global) + next
// kt's h-fragment and scale/shift prefetched one tile ahead (+4 VGPR, no barriers).
// Tripwire: WRITE_SIZE must stay 100 MB (outputs only) — spill shows up there.
template <int K, bool BN>
__global__ __launch_bounds__(256) void k_linear2(
    const float* __restrict__ h, const float* __restrict__ WL,
    const float* __restrict__ WR, const float* __restrict__ bl,
    const float* __restrict__ br, const float* __restrict__ scale,
    const float* __restrict__ shift, float* __restrict__ outl,
    float* __restrict__ outr)
{
    int tid = threadIdx.x;
    int lane = tid & 63, wave = tid >> 6;
    int row0 = blockIdx.x * 32 + wave * 8;
    int q = lane >> 4;       // 0..3
    int kl = lane & 15;      // 0..15
    float4 accL[8], accR[8];
    #pragma unroll
    for (int r = 0; r < 8; ++r) {
        accL[r] = make_float4(0.f, 0.f, 0.f, 0.f);
        accR[r] = make_float4(0.f, 0.f, 0.f, 0.f);
    }

    int rowA = row0 + q;     if (rowA >= NN) rowA = NN - 1;
    int rowB = row0 + 4 + q; if (rowB >= NN) rowB = NN - 1;
    const float* hA = h + (size_t)rowA * K;
    const float* hB = h + (size_t)rowB * K;

    float rawA = hA[kl], rawB = hB[kl];
    float scv = BN ? scale[kl] : 1.f, shv = BN ? shift[kl] : 0.f;

    for (int kt = 0; kt < K / 16; ++kt) {
        float hreg[2];
        hreg[0] = BN ? fmaxf(fmaf(rawA, scv, shv), 0.f) : rawA;
        hreg[1] = BN ? fmaxf(fmaf(rawB, scv, shv), 0.f) : rawB;
        float nrA = 0.f, nrB = 0.f, nsc = 1.f, nsh = 0.f;
        if (kt + 1 < K / 16) {      // prefetch next tile's h + BN consts
            int o = (kt + 1) * 16 + kl;
            nrA = hA[o]; nrB = hB[o];
            if (BN) { nsc = scale[o]; nsh = shift[o]; }
        }
        #pragma unroll
        for (int k = 0; k < 16; ++k) {
            float4 wl4 = ((const float4*)(WL + (size_t)(kt * 16 + k) * 256))[lane];
            float4 wr4 = ((const float4*)(WR + (size_t)(kt * 16 + k) * 256))[lane];
            #pragma unroll
            for (int j = 0; j < 8; ++j) {
                float hb = rdlane(hreg[j >> 2], (j & 3) * 16 + k);
                accL[j] = fma4(hb, wl4, accL[j]);
                accR[j] = fma4(hb, wr4, accR[j]);
            }
        }
        rawA = nrA; rawB = nrB; scv = nsc; shv = nsh;
    }
    float4 bl4 = ((const float4*)bl)[lane];
    float4 br4 = ((const float4*)br)[lane];
    #pragma unroll
    for (int j = 0; j < 8; ++j) {
        int row = row0 + j;
        if (row < NN) {
            float4 o;
            o.x = accL[j].x + bl4.x; o.y = accL[j].y + bl4.y;
            o.z = accL[j].z + bl4.z; o.w = accL[j].w + bl4.w;
            ((float4*)(outl + (size_t)row * 256))[lane] = o;
            float4 pp;
            pp.x = accR[j].x + br4.x; pp.y = accR[j].y + br4.y;
            pp.z = accR[j].z + br4.z; pp.w = accR[j].w + br4.w;
            ((float4*)(outr + (size_t)row * 256))[lane] = pp;
        }
    }
}

// ---------------- fused attention: wave per NPW dst nodes, 2-deep batch pipeline ------
// Latency-bound kernel (VALU work ~14 us, HBM floor ~52 us, measured ~170 us):
// two 4-edge batches in flight (ping-pong slots, compile-time indices -> no scratch).
template <bool CONCAT, int NPW>
__global__ __launch_bounds__(256) void k_attn(
    const float* __restrict__ xl, const float* __restrict__ xr,
    const float* __restrict__ eas, const float* __restrict__ We,
    const float* __restrict__ att, const int* __restrict__ srcs,
    const int* __restrict__ offs, const float* __restrict__ bias,
    float* __restrict__ out)
{
    int tid = threadIdx.x;
    int lane = tid & 63, wave = tid >> 6;
    float4 wr[16];
    #pragma unroll
    for (int k = 0; k < 16; ++k) wr[k] = ((const float4*)(We + k * 256))[lane];
    float4 ar = ((const float4*)att)[lane];

    int g16 = lane >> 4;
    int k16 = lane & 15;
    int nodebase = (blockIdx.x * 4 + wave) * NPW;
    if (nodebase >= NN) return;

    for (int nn = 0; nn < NPW; ++nn) {
        int n = nodebase + nn;
        if (n >= NN) break;
        int beg = offs[n], end = offs[n + 1];
        float4 xr4 = ((const float4*)(xr + (size_t)n * 256))[lane];

        float m = -INFINITY, ssum = 0.f;
        float4 acc = make_float4(0.f, 0.f, 0.f, 0.f);

        float neaA = 0.f, neaB = 0.f;
        float4 nxA0, nxA1, nxA2, nxA3, nxB0, nxB1, nxB2, nxB3;

        auto ldsrc = [&](int i, float& nea, float4& n0, float4& n1, float4& n2, float4& n3) {
            int idx = i + g16;
            if (idx > end - 1) idx = end - 1;
            nea = eas[(size_t)idx * 16 + k16];
            int sv = srcs[idx];
            int s0 = __builtin_amdgcn_readlane(sv, 0);
            int s1 = __builtin_amdgcn_readlane(sv, 16);
            int s2 = __builtin_amdgcn_readlane(sv, 32);
            int s3 = __builtin_amdgcn_readlane(sv, 48);
            n0 = ((const float4*)(xl + (size_t)s0 * 256))[lane];
            n1 = ((const float4*)(xl + (size_t)s1 * 256))[lane];
            n2 = ((const float4*)(xl + (size_t)s2 * 256))[lane];
            n3 = ((const float4*)(xl + (size_t)s3 * 256))[lane];
        };

        auto process = [&](int i, float cea, float4 x0, float4 x1, float4 x2, float4 x3) {
            float p[4];
            #pragma unroll
            for (int g = 0; g < 4; ++g) {
                float4 xg = (g == 0) ? x0 : (g == 1) ? x1 : (g == 2) ? x2 : x3;
                float4 em = xr4;  // xr folded into accumulator init
                #pragma unroll
                for (int k = 0; k < 16; ++k) {
                    float a = rdlane(cea, g * 16 + k);
                    em.x = fmaf(a, wr[k].x, em.x);
                    em.y = fmaf(a, wr[k].y, em.y);
                    em.z = fmaf(a, wr[k].z, em.z);
                    em.w = fmaf(a, wr[k].w, em.w);
                }
                float z0 = xg.x + em.x;
                float z1 = xg.y + em.y;
                float z2 = xg.z + em.z;
                float z3 = xg.w + em.w;
                z0 = (z0 > 0.f) ? z0 : kSlope * z0;
                z1 = (z1 > 0.f) ? z1 : kSlope * z1;
                z2 = (z2 > 0.f) ? z2 : kSlope * z2;
                z3 = (z3 > 0.f) ? z3 : kSlope * z3;
                float pv = fmaf(z0, ar.x, fmaf(z1, ar.y, fmaf(z2, ar.z, z3 * ar.w)));
                pv = sum16(pv);  // per-head logit (16-lane group), VALU-only DPP
                p[g] = (i + g < end) ? pv : -INFINITY;
            }
            float pm = fmaxf(fmaxf(p[0], p[1]), fmaxf(p[2], p[3]));
            float mn = fmaxf(m, pm);
            float sc = __expf(m - mn);
            float w0 = __expf(p[0] - mn);
            float w1 = __expf(p[1] - mn);
            float w2 = __expf(p[2] - mn);
            float w3 = __expf(p[3] - mn);
            ssum = fmaf(ssum, sc, (w0 + w1) + (w2 + w3));
            acc.x = fmaf(acc.x, sc, fmaf(w0, x0.x, fmaf(w1, x1.x, fmaf(w2, x2.x, w3 * x3.x))));
            acc.y = fmaf(acc.y, sc, fmaf(w0, x0.y, fmaf(w1, x1.y, fmaf(w2, x2.y, w3 * x3.y))));
            acc.z = fmaf(acc.z, sc, fmaf(w0, x0.z, fmaf(w1, x1.z, fmaf(w2, x2.z, w3 * x3.z))));
            acc.w = fmaf(acc.w, sc, fmaf(w0, x0.w, fmaf(w1, x1.w, fmaf(w2, x2.w, w3 * x3.w))));
            m = mn;
        };

        if (beg < end) ldsrc(beg, neaA, nxA0, nxA1, nxA2, nxA3);
        if (beg + 4 < end) ldsrc(beg + 4, neaB, nxB0, nxB1, nxB2, nxB3);

        for (int i = beg; i < end; i += 8) {
            {   // consume A, refill A for i+8
                float cea = neaA;
                float4 c0 = nxA0, c1 = nxA1, c2 = nxA2, c3 = nxA3;
                if (i + 8 < end) ldsrc(i + 8, neaA, nxA0, nxA1, nxA2, nxA3);
                process(i, cea, c0, c1, c2, c3);
            }
            if (i + 4 < end) {  // consume B, refill B for i+12
                float cea = neaB;
                float4 c0 = nxB0, c1 = nxB1, c2 = nxB2, c3 = nxB3;
                if (i + 12 < end) ldsrc(i + 12, neaB, nxB0, nxB1, nxB2, nxB3);
                process(i + 4, cea, c0, c1, c2, c3);
            }
        }

        float inv = 1.f / (ssum + 1e-16f);
        if (CONCAT) {
            float4 b4 = ((const float4*)bias)[lane];
            float4 o;
            o.x = fmaf(acc.x, inv, b4.x);
            o.y = fmaf(acc.y, inv, b4.y);
            o.z = fmaf(acc.z, inv, b4.z);
            o.w = fmaf(acc.w, inv, b4.w);
            ((float4*)(out + (size_t)n * 256))[lane] = o;
        } else {
            float v0 = acc.x * inv, v1 = acc.y * inv, v2 = acc.z * inv, v3 = acc.w * inv;
            v0 += __shfl_xor(v0, 16, 64); v0 += __shfl_xor(v0, 32, 64);
            v1 += __shfl_xor(v1, 16, 64); v1 += __shfl_xor(v1, 32, 64);
            v2 += __shfl_xor(v2, 16, 64); v2 += __shfl_xor(v2, 32, 64);
            v3 += __shfl_xor(v3, 16, 64); v3 += __shfl_xor(v3, 32, 64);
            if (lane < 16) {
                float4 b4 = ((const float4*)bias)[lane];
                float4 o;
                o.x = fmaf(0.25f, v0, b4.x);
                o.y = fmaf(0.25f, v1, b4.y);
                o.z = fmaf(0.25f, v2, b4.z);
                o.w = fmaf(0.25f, v3, b4.w);
                ((float4*)(out + (size_t)n * 64))[lane] = o;
            }
        }
    }
}

// ---------------- batchnorm stats (sum, sumsq per channel) ----------------
template <int CH>
__global__ __launch_bounds__(256) void k_bn_stats(const float* __restrict__ h,
                                                  float* __restrict__ sum,
                                                  float* __restrict__ sumsq)
{
    constexpr int RP = 256 / CH;
    int tid = threadIdx.x;
    int c = tid % CH;
    int rsub = tid / CH;
    float s = 0.f, q = 0.f;
    for (int n = blockIdx.x * RP + rsub; n < NN; n += gridDim.x * RP) {
        float v = h[(size_t)n * CH + c];
        s += v; q = fmaf(v, v, q);
    }
    __shared__ float ls[256], lq[256];
    ls[tid] = s; lq[tid] = q;
    __syncthreads();
    if (tid < CH) {
        #pragma unroll
        for (int r = 1; r < RP; ++r) { s += ls[tid + r * CH]; q += lq[tid + r * CH]; }
        atomicAdd(&sum[tid], s);
        atomicAdd(&sumsq[tid], q);
    }
}

__global__ void k_bn_finalize(const float* __restrict__ sum, const float* __restrict__ sumsq,
                              const float* __restrict__ g, const float* __restrict__ beta,
                              float* __restrict__ scale, float* __restrict__ shift, int CH)
{
    int c = threadIdx.x;
    if (c >= CH) return;
    float inv_n = 1.f / (float)NN;
    float mu = sum[c] * inv_n;
    float var = sumsq[c] * inv_n - mu * mu;
    float sc = g[c] / sqrtf(var + kBnEps);
    scale[c] = sc;
    shift[c] = fmaf(-mu, sc, beta[c]);
}

// ---------------- fused BN + mean-pool + MLP head: one block per graph ----------------
// graph bounds found inline (binary search on sorted batch) — k_gbounds removed.
__global__ __launch_bounds__(256) void k_pool_mlp(
    const float* __restrict__ h2, const float* __restrict__ scale,
    const float* __restrict__ shift, const int* __restrict__ batch,
    const float* __restrict__ Wm1, const float* __restrict__ bm1,
    const float* __restrict__ Wm2, const float* __restrict__ bm2,
    const float* __restrict__ Wm3, const float* __restrict__ bm3,
    float* __restrict__ out)
{
    int g = blockIdx.x, tid = threadIdx.x;
    int lane = tid & 63, wave = tid >> 6;
    __shared__ int sb[2];
    if (tid < 2) {
        int target = g + tid;
        int lo = 0, hi = NN;
        while (lo < hi) {
            int mid = (lo + hi) >> 1;
            if (batch[mid] < target) lo = mid + 1; else hi = mid;
        }
        sb[tid] = lo;
    }
    __syncthreads();
    int s = sb[0], e = sb[1];
    float sc = scale[lane], sh = shift[lane];
    float acc = 0.f;
    for (int n = s + wave; n < e; n += 4)
        acc += fmaf(h2[(size_t)n * 64 + lane], sc, sh);
    __shared__ float red[4][64];
    red[wave][lane] = acc;
    __syncthreads();
    __shared__ float p[64], z1[32], z2[16];
    if (tid < 64) {
        float cnt = (float)(e - s);
        float a = red[0][tid] + red[1][tid] + red[2][tid] + red[3][tid];
        p[tid] = a / fmaxf(cnt, 1.f);
    }
    __syncthreads();
    if (tid < 32) {
        float a = bm1[tid];
        #pragma unroll
        for (int k = 0; k < 64; ++k) a = fmaf(p[k], Wm1[k * 32 + tid], a);
        z1[tid] = fmaxf(a, 0.f);
    }
    __syncthreads();
    if (tid < 16) {
        float a = bm2[tid];
        #pragma unroll
        for (int k = 0; k < 32; ++k) a = fmaf(z1[k], Wm2[k * 16 + tid], a);
        z2[tid] = fmaxf(a, 0.f);
    }
    __syncthreads();
    if (tid == 0) {
        float a = bm3[0];
        #pragma unroll
        for (int k = 0; k < 16; ++k) a = fmaf(z2[k], Wm3[k], a);
        out[g] = a;
    }
}

// ---------------- host launcher ----------------
extern "C" void kernel_launch(void* const* d_in, const int* in_sizes, int n_in,
                              void* d_out, int out_size, void* d_ws, size_t ws_size,
                              hipStream_t stream)
{
    const float* x     = (const float*)d_in[0];
    const float* ea    = (const float*)d_in[1];
    const int*   ei    = (const int*)d_in[2];
    const int*   bat   = (const int*)d_in[3];
    const float* W_in  = (const float*)d_in[4];
    const float* b_in  = (const float*)d_in[5];
    const float* Wl0   = (const float*)d_in[6];
    const float* bl0   = (const float*)d_in[7];
    const float* Wr0   = (const float*)d_in[8];
    const float* br0   = (const float*)d_in[9];
    const float* We0   = (const float*)d_in[10];
    const float* att0  = (const float*)d_in[11];
    const float* bias0 = (const float*)d_in[12];
    const float* g0    = (const float*)d_in[13];
    const float* beta0 = (const float*)d_in[14];
    const float* Wl1   = (const float*)d_in[15];
    const float* bl1   = (const float*)d_in[16];
    const float* Wr1   = (const float*)d_in[17];
    const float* br1   = (const float*)d_in[18];
    const float* We1   = (const float*)d_in[19];
    const float* att1  = (const float*)d_in[20];
    const float* bias1 = (const float*)d_in[21];
    const float* g1    = (const float*)d_in[22];
    const float* beta1 = (const float*)d_in[23];
    const float* Wm1   = (const float*)d_in[24];
    const float* bm1   = (const float*)d_in[25];
    const float* Wm2   = (const float*)d_in[26];
    const float* bm2   = (const float*)d_in[27];
    const float* Wm3   = (const float*)d_in[28];
    const float* bm3   = (const float*)d_in[29];
    const int* src = ei;
    const int* dst = ei + NE;
    float* out = (float*)d_out;

    char* p = (char*)d_ws;
    auto take = [&](size_t nbytes) -> char* {
        char* q = p;
        p += (nbytes + 255) & ~(size_t)255;
        return q;
    };
    // ---- zero zone (one memset) ----
    char* z0 = p;
    int*   hist   = (int*)take((size_t)NN * 4);
    float* bns0   = (float*)take(256 * 4);
    float* bnq0   = (float*)take(256 * 4);
    float* bns1   = (float*)take(64 * 4);
    float* bnq1   = (float*)take(64 * 4);
    size_t zbytes = (size_t)(p - z0);
    // ---- rest of workspace ----
    int*   offs   = (int*)take((size_t)(NN + 1) * 4);
    int*   curs   = (int*)take((size_t)NN * 4);
    int*   bsum   = (int*)take((size_t)SB * 4);
    int*   srcs   = (int*)take((size_t)NE * 4);
    float* eas    = (float*)take((size_t)NE * 16 * 4);
    float* h2     = (float*)take((size_t)NN * 64 * 4);
    float* xl     = (float*)take((size_t)NN * 256 * 4);
    float* xr     = (float*)take((size_t)NN * 256 * 4);
    float* h1     = (float*)take((size_t)NN * 256 * 4);
    float* scale0 = (float*)take(256 * 4);
    float* shift0 = (float*)take(256 * 4);
    float* scale1 = (float*)take(64 * 4);
    float* shift1 = (float*)take(64 * 4);

    hipMemsetAsync(z0, 0, zbytes, stream);

    k_hist<<<(NE + 255) / 256, 256, 0, stream>>>(dst, hist);
    k_scanA<<<SB, 256, 0, stream>>>(hist, offs, bsum);
    k_scanB<<<1, 256, 0, stream>>>(bsum);
    k_scanC<<<SB, 256, 0, stream>>>(hist, bsum, offs, curs);
    k_scatter<<<(NE + 255) / 256, 256, 0, stream>>>(dst, src, ea, curs, srcs, eas);

    constexpr int NPW = 2;
    int attn_blocks = (NN + 4 * NPW - 1) / (4 * NPW);
    int lin_blocks = (NN + 31) / 32;

    // ---- GATv2 layer 0 (input proj fused into dual linear) ----
    k_lin0<<<lin_blocks, 256, 0, stream>>>(
        x, W_in, b_in, Wl0, Wr0, bl0, br0, xl, xr);
    k_attn<true, NPW><<<attn_blocks, 256, 0, stream>>>(
        xl, xr, eas, We0, att0, srcs, offs, bias0, h1);
    k_bn_stats<256><<<256, 256, 0, stream>>>(h1, bns0, bnq0);
    k_bn_finalize<<<1, 256, 0, stream>>>(bns0, bnq0, g0, beta0, scale0, shift0, 256);

    // ---- GATv2 layer 1 (BN0+relu folded into linear input reads) ----
    k_linear2<256, true><<<lin_blocks, 256, 0, stream>>>(
        h1, Wl1, Wr1, bl1, br1, scale0, shift0, xl, xr);
    k_attn<false, NPW><<<attn_blocks, 256, 0, stream>>>(
        xl, xr, eas, We1, att1, srcs, offs, bias1, h2);
    k_bn_stats<64><<<256, 256, 0, stream>>>(h2, bns1, bnq1);
    k_bn_finalize<<<1, 64, 0, stream>>>(bns1, bnq1, g1, beta1, scale1, shift1, 64);

    // ---- fused BN + pool + MLP (graph bounds inline) ----
    k_pool_mlp<<<NG, 256, 0, stream>>>(h2, scale1, shift1, bat,
                                       Wm1, bm1, Wm2, bm2, Wm3, bm3, out);
}

// Round 13
// 803.622 us; speedup vs baseline: 1.0715x; 1.0715x over previous
//
#include <hip/hip_runtime.h>
#include <math.h>

constexpr int NN = 50000;
constexpr int NE = 600000;
constexpr int NG = 256;
constexpr int SB = (NN + 255) / 256;  // scan blocks = 196
constexpr float kBnEps = 1e-5f;
constexpr float kSlope = 0.2f;

__device__ __forceinline__ float rdlane(float v, int l) {
    return __builtin_bit_cast(float, __builtin_amdgcn_readlane(__builtin_bit_cast(int, v), l));
}

// DPP-based add: v += v[permuted lane] — VALU only, no LDS pipe.
template <int CTRL>
__device__ __forceinline__ float dppadd(float v) {
    int t = __builtin_amdgcn_mov_dpp(__builtin_bit_cast(int, v), CTRL, 0xF, 0xF, true);
    return v + __builtin_bit_cast(float, t);
}
// sum over each 16-lane group (all 16 lanes end with the group sum)
__device__ __forceinline__ float sum16(float v) {
    v = dppadd<0xB1>(v);    // quad_perm [1,0,3,2]
    v = dppadd<0x4E>(v);    // quad_perm [2,3,0,1]
    v = dppadd<0x141>(v);   // row_half_mirror
    v = dppadd<0x140>(v);   // row_mirror
    return v;
}

__device__ __forceinline__ float4 fma4(float a, float4 b, float4 c) {
    c.x = fmaf(a, b.x, c.x); c.y = fmaf(a, b.y, c.y);
    c.z = fmaf(a, b.z, c.z); c.w = fmaf(a, b.w, c.w);
    return c;
}

// ---------------- counting sort of edges by dst ----------------
__global__ __launch_bounds__(256) void k_hist(const int* __restrict__ dst, int* __restrict__ cnt)
{
    int e = blockIdx.x * 256 + threadIdx.x;
    if (e < NE) atomicAdd(&cnt[dst[e]], 1);
}

// parallel scan, 3 kernels: per-block inclusive scan, block-sum scan, fixup
__global__ __launch_bounds__(256) void k_scanA(const int* __restrict__ cnt,
                                               int* __restrict__ offs, int* __restrict__ bsum)
{
    __shared__ int s[256];
    int tid = threadIdx.x;
    int i = blockIdx.x * 256 + tid;
    int v = (i < NN) ? cnt[i] : 0;
    s[tid] = v;
    __syncthreads();
    #pragma unroll
    for (int d = 1; d < 256; d <<= 1) {
        int u = (tid >= d) ? s[tid - d] : 0;
        __syncthreads();
        s[tid] += u;
        __syncthreads();
    }
    if (i < NN) offs[i] = s[tid];           // block-local inclusive
    if (tid == 255) bsum[blockIdx.x] = s[255];
}

__global__ __launch_bounds__(256) void k_scanB(int* __restrict__ bsum)
{
    __shared__ int s[256];
    int t = threadIdx.x;
    int v = (t < SB) ? bsum[t] : 0;
    s[t] = v;
    __syncthreads();
    #pragma unroll
    for (int d = 1; d < 256; d <<= 1) {
        int u = (t >= d) ? s[t - d] : 0;
        __syncthreads();
        s[t] += u;
        __syncthreads();
    }
    if (t < SB) bsum[t] = s[t];             // inclusive over block sums
}

__global__ __launch_bounds__(256) void k_scanC(const int* __restrict__ cnt,
                                               const int* __restrict__ bsum,
                                               int* __restrict__ offs, int* __restrict__ cur)
{
    int i = blockIdx.x * 256 + threadIdx.x;
    if (i > NN) return;
    if (i == NN) { offs[NN] = NE; return; }
    int pre = (blockIdx.x > 0) ? bsum[blockIdx.x - 1] : 0;
    int v = offs[i] - cnt[i] + pre;         // global exclusive
    offs[i] = v;
    cur[i] = v;
}

// scatter edges into dst-sorted order; also reorder edge_attr rows (eas)
__global__ __launch_bounds__(256) void k_scatter(const int* __restrict__ dst,
                                                 const int* __restrict__ src,
                                                 const float* __restrict__ ea,
                                                 int* __restrict__ cur,
                                                 int* __restrict__ srcs,
                                                 float* __restrict__ eas)
{
    int e = blockIdx.x * 256 + threadIdx.x;
    if (e < NE) {
        int p = atomicAdd(&cur[dst[e]], 1);
        srcs[p] = src[e];
        const float4* s4 = (const float4*)(ea + (size_t)e * 16);
        float4* d4 = (float4*)(eas + (size_t)p * 16);
        d4[0] = s4[0]; d4[1] = s4[1]; d4[2] = s4[2]; d4[3] = s4[3];
    }
}

// ---------------- fused layer-0: h0 = relu(x@Win+bin) in regs, then dual GEMM ------
// 32 rows/block (8/wave). h0 NEVER touches memory. No LDS, no barriers.
__global__ __launch_bounds__(256) void k_lin0(
    const float* __restrict__ x, const float* __restrict__ Win,
    const float* __restrict__ bin, const float* __restrict__ WL,
    const float* __restrict__ WR, const float* __restrict__ bl,
    const float* __restrict__ br, float* __restrict__ outl,
    float* __restrict__ outr)
{
    int tid = threadIdx.x;
    int lane = tid & 63, wave = tid >> 6;
    int row0 = blockIdx.x * 32 + wave * 8;

    // prologue: h0 for 8 rows, lane = channel
    float xreg[8];
    #pragma unroll
    for (int j = 0; j < 8; ++j) {
        int row = row0 + j; if (row >= NN) row = NN - 1;
        xreg[j] = x[(size_t)row * 64 + lane];
    }
    float h0r[8];
    float b0 = bin[lane];
    #pragma unroll
    for (int j = 0; j < 8; ++j) h0r[j] = b0;
    for (int k = 0; k < 64; ++k) {
        float w = Win[k * 64 + lane];
        #pragma unroll
        for (int j = 0; j < 8; ++j) h0r[j] = fmaf(rdlane(xreg[j], k), w, h0r[j]);
    }
    #pragma unroll
    for (int j = 0; j < 8; ++j) h0r[j] = fmaxf(h0r[j], 0.f);

    // dual GEMM K=64, h broadcast straight from registers
    float4 accL[8], accR[8];
    #pragma unroll
    for (int j = 0; j < 8; ++j) {
        accL[j] = make_float4(0.f, 0.f, 0.f, 0.f);
        accR[j] = make_float4(0.f, 0.f, 0.f, 0.f);
    }
    for (int k = 0; k < 64; ++k) {
        float4 wl4 = ((const float4*)(WL + (size_t)k * 256))[lane];
        float4 wr4 = ((const float4*)(WR + (size_t)k * 256))[lane];
        #pragma unroll
        for (int j = 0; j < 8; ++j) {
            float hb = rdlane(h0r[j], k);
            accL[j] = fma4(hb, wl4, accL[j]);
            accR[j] = fma4(hb, wr4, accR[j]);
        }
    }
    float4 bl4 = ((const float4*)bl)[lane];
    float4 br4 = ((const float4*)br)[lane];
    #pragma unroll
    for (int j = 0; j < 8; ++j) {
        int row = row0 + j;
        if (row < NN) {
            float4 o;
            o.x = accL[j].x + bl4.x; o.y = accL[j].y + bl4.y;
            o.z = accL[j].z + bl4.z; o.w = accL[j].w + bl4.w;
            ((float4*)(outl + (size_t)row * 256))[lane] = o;
            float4 pp;
            pp.x = accR[j].x + br4.x; pp.y = accR[j].y + br4.y;
            pp.z = accR[j].z + br4.z; pp.w = accR[j].w + br4.w;
            ((float4*)(outr + (size_t)row * 256))[lane] = pp;
        }
    }
}

// ---------------- dual linear K=256 (FROZEN r9/r11 shape) ----------------
// 32 rows/block (8/wave), NO LDS, NO barriers, W direct from global (L1/L2-hot).
// VGPR 68, zero spill, 184 us. Three improvement attempts all regressed:
// r7/r8 (reg-prefetch W across barriers -> 850 MB spill), r10 (16 rows/wave ->
// 124 VGPR, waves starve), r12 (h-prefetch -> compiler squeezes to 64 VGPR,
// IPC drops). Do not touch.
template <int K, bool BN>
__global__ __launch_bounds__(256) void k_linear2(
    const float* __restrict__ h, const float* __restrict__ WL,
    const float* __restrict__ WR, const float* __restrict__ bl,
    const float* __restrict__ br, const float* __restrict__ scale,
    const float* __restrict__ shift, float* __restrict__ outl,
    float* __restrict__ outr)
{
    int tid = threadIdx.x;
    int lane = tid & 63, wave = tid >> 6;
    int row0 = blockIdx.x * 32 + wave * 8;
    int q = lane >> 4;       // 0..3
    int kl = lane & 15;      // 0..15
    float4 accL[8], accR[8];
    #pragma unroll
    for (int r = 0; r < 8; ++r) {
        accL[r] = make_float4(0.f, 0.f, 0.f, 0.f);
        accR[r] = make_float4(0.f, 0.f, 0.f, 0.f);
    }

    for (int kt = 0; kt < K / 16; ++kt) {
        float hreg[2];
        float sc = 1.f, sh = 0.f;
        if (BN) { sc = scale[kt * 16 + kl]; sh = shift[kt * 16 + kl]; }
        #pragma unroll
        for (int r = 0; r < 2; ++r) {
            int row = row0 + 4 * r + q;
            if (row >= NN) row = NN - 1;
            float v = h[(size_t)row * K + kt * 16 + kl];
            if (BN) v = fmaxf(fmaf(v, sc, sh), 0.f);
            hreg[r] = v;
        }
        #pragma unroll
        for (int k = 0; k < 16; ++k) {
            float4 wl4 = ((const float4*)(WL + (size_t)(kt * 16 + k) * 256))[lane];
            float4 wr4 = ((const float4*)(WR + (size_t)(kt * 16 + k) * 256))[lane];
            #pragma unroll
            for (int j = 0; j < 8; ++j) {
                float hb = rdlane(hreg[j >> 2], (j & 3) * 16 + k);
                accL[j] = fma4(hb, wl4, accL[j]);
                accR[j] = fma4(hb, wr4, accR[j]);
            }
        }
    }
    float4 bl4 = ((const float4*)bl)[lane];
    float4 br4 = ((const float4*)br)[lane];
    #pragma unroll
    for (int j = 0; j < 8; ++j) {
        int row = row0 + j;
        if (row < NN) {
            float4 o;
            o.x = accL[j].x + bl4.x; o.y = accL[j].y + bl4.y;
            o.z = accL[j].z + bl4.z; o.w = accL[j].w + bl4.w;
            ((float4*)(outl + (size_t)row * 256))[lane] = o;
            float4 pp;
            pp.x = accR[j].x + br4.x; pp.y = accR[j].y + br4.y;
            pp.z = accR[j].z + br4.z; pp.w = accR[j].w + br4.w;
            ((float4*)(outr + (size_t)row * 256))[lane] = pp;
        }
    }
}

// ---------------- fused attention (r11 shape): wave per NPW nodes, 1-deep prefetch ----
// r12 lesson: 2-deep pipeline (+8 float4 in flight) regressed ~+30 us via VGPR
// pressure; single-depth with NPW=2 is the measured best.
template <bool CONCAT, int NPW>
__global__ __launch_bounds__(256) void k_attn(
    const float* __restrict__ xl, const float* __restrict__ xr,
    const float* __restrict__ eas, const float* __restrict__ We,
    const float* __restrict__ att, const int* __restrict__ srcs,
    const int* __restrict__ offs, const float* __restrict__ bias,
    float* __restrict__ out)
{
    int tid = threadIdx.x;
    int lane = tid & 63, wave = tid >> 6;
    float4 wr[16];
    #pragma unroll
    for (int k = 0; k < 16; ++k) wr[k] = ((const float4*)(We + k * 256))[lane];
    float4 ar = ((const float4*)att)[lane];

    int g16 = lane >> 4;
    int k16 = lane & 15;
    int nodebase = (blockIdx.x * 4 + wave) * NPW;
    if (nodebase >= NN) return;

    for (int nn = 0; nn < NPW; ++nn) {
        int n = nodebase + nn;
        if (n >= NN) break;
        int beg = offs[n], end = offs[n + 1];
        float4 xr4 = ((const float4*)(xr + (size_t)n * 256))[lane];

        float m = -INFINITY, ssum = 0.f;
        float4 acc = make_float4(0.f, 0.f, 0.f, 0.f);

        float nea = 0.f;
        float4 nx0, nx1, nx2, nx3;

        auto loadbatch = [&](int i) {
            int idx = i + g16;
            if (idx > end - 1) idx = end - 1;
            nea = eas[(size_t)idx * 16 + k16];
            int sv = srcs[idx];
            int s0 = __builtin_amdgcn_readlane(sv, 0);
            int s1 = __builtin_amdgcn_readlane(sv, 16);
            int s2 = __builtin_amdgcn_readlane(sv, 32);
            int s3 = __builtin_amdgcn_readlane(sv, 48);
            nx0 = ((const float4*)(xl + (size_t)s0 * 256))[lane];
            nx1 = ((const float4*)(xl + (size_t)s1 * 256))[lane];
            nx2 = ((const float4*)(xl + (size_t)s2 * 256))[lane];
            nx3 = ((const float4*)(xl + (size_t)s3 * 256))[lane];
        };

        if (beg < end) loadbatch(beg);

        for (int i = beg; i < end; i += 4) {
            float cea = nea;
            float4 x0 = nx0, x1 = nx1, x2 = nx2, x3 = nx3;
            if (i + 4 < end) loadbatch(i + 4);

            float p[4];
            #pragma unroll
            for (int g = 0; g < 4; ++g) {
                float4 xg = (g == 0) ? x0 : (g == 1) ? x1 : (g == 2) ? x2 : x3;
                float4 em = xr4;  // xr folded into accumulator init
                #pragma unroll
                for (int k = 0; k < 16; ++k) {
                    float a = rdlane(cea, g * 16 + k);
                    em.x = fmaf(a, wr[k].x, em.x);
                    em.y = fmaf(a, wr[k].y, em.y);
                    em.z = fmaf(a, wr[k].z, em.z);
                    em.w = fmaf(a, wr[k].w, em.w);
                }
                float z0 = xg.x + em.x;
                float z1 = xg.y + em.y;
                float z2 = xg.z + em.z;
                float z3 = xg.w + em.w;
                z0 = (z0 > 0.f) ? z0 : kSlope * z0;
                z1 = (z1 > 0.f) ? z1 : kSlope * z1;
                z2 = (z2 > 0.f) ? z2 : kSlope * z2;
                z3 = (z3 > 0.f) ? z3 : kSlope * z3;
                float pv = fmaf(z0, ar.x, fmaf(z1, ar.y, fmaf(z2, ar.z, z3 * ar.w)));
                pv = sum16(pv);  // per-head logit (16-lane group), VALU-only DPP
                p[g] = (i + g < end) ? pv : -INFINITY;
            }
            float pm = fmaxf(fmaxf(p[0], p[1]), fmaxf(p[2], p[3]));
            float mn = fmaxf(m, pm);
            float sc = __expf(m - mn);
            float w0 = __expf(p[0] - mn);
            float w1 = __expf(p[1] - mn);
            float w2 = __expf(p[2] - mn);
            float w3 = __expf(p[3] - mn);
            ssum = fmaf(ssum, sc, (w0 + w1) + (w2 + w3));
            acc.x = fmaf(acc.x, sc, fmaf(w0, x0.x, fmaf(w1, x1.x, fmaf(w2, x2.x, w3 * x3.x))));
            acc.y = fmaf(acc.y, sc, fmaf(w0, x0.y, fmaf(w1, x1.y, fmaf(w2, x2.y, w3 * x3.y))));
            acc.z = fmaf(acc.z, sc, fmaf(w0, x0.z, fmaf(w1, x1.z, fmaf(w2, x2.z, w3 * x3.z))));
            acc.w = fmaf(acc.w, sc, fmaf(w0, x0.w, fmaf(w1, x1.w, fmaf(w2, x2.w, w3 * x3.w))));
            m = mn;
        }

        float inv = 1.f / (ssum + 1e-16f);
        if (CONCAT) {
            float4 b4 = ((const float4*)bias)[lane];
            float4 o;
            o.x = fmaf(acc.x, inv, b4.x);
            o.y = fmaf(acc.y, inv, b4.y);
            o.z = fmaf(acc.z, inv, b4.z);
            o.w = fmaf(acc.w, inv, b4.w);
            ((float4*)(out + (size_t)n * 256))[lane] = o;
        } else {
            float v0 = acc.x * inv, v1 = acc.y * inv, v2 = acc.z * inv, v3 = acc.w * inv;
            v0 += __shfl_xor(v0, 16, 64); v0 += __shfl_xor(v0, 32, 64);
            v1 += __shfl_xor(v1, 16, 64); v1 += __shfl_xor(v1, 32, 64);
            v2 += __shfl_xor(v2, 16, 64); v2 += __shfl_xor(v2, 32, 64);
            v3 += __shfl_xor(v3, 16, 64); v3 += __shfl_xor(v3, 32, 64);
            if (lane < 16) {
                float4 b4 = ((const float4*)bias)[lane];
                float4 o;
                o.x = fmaf(0.25f, v0, b4.x);
                o.y = fmaf(0.25f, v1, b4.y);
                o.z = fmaf(0.25f, v2, b4.z);
                o.w = fmaf(0.25f, v3, b4.w);
                ((float4*)(out + (size_t)n * 64))[lane] = o;
            }
        }
    }
}

// ---------------- batchnorm stats (sum, sumsq per channel) ----------------
template <int CH>
__global__ __launch_bounds__(256) void k_bn_stats(const float* __restrict__ h,
                                                  float* __restrict__ sum,
                                                  float* __restrict__ sumsq)
{
    constexpr int RP = 256 / CH;
    int tid = threadIdx.x;
    int c = tid % CH;
    int rsub = tid / CH;
    float s = 0.f, q = 0.f;
    for (int n = blockIdx.x * RP + rsub; n < NN; n += gridDim.x * RP) {
        float v = h[(size_t)n * CH + c];
        s += v; q = fmaf(v, v, q);
    }
    __shared__ float ls[256], lq[256];
    ls[tid] = s; lq[tid] = q;
    __syncthreads();
    if (tid < CH) {
        #pragma unroll
        for (int r = 1; r < RP; ++r) { s += ls[tid + r * CH]; q += lq[tid + r * CH]; }
        atomicAdd(&sum[tid], s);
        atomicAdd(&sumsq[tid], q);
    }
}

__global__ void k_bn_finalize(const float* __restrict__ sum, const float* __restrict__ sumsq,
                              const float* __restrict__ g, const float* __restrict__ beta,
                              float* __restrict__ scale, float* __restrict__ shift, int CH)
{
    int c = threadIdx.x;
    if (c >= CH) return;
    float inv_n = 1.f / (float)NN;
    float mu = sum[c] * inv_n;
    float var = sumsq[c] * inv_n - mu * mu;
    float sc = g[c] / sqrtf(var + kBnEps);
    scale[c] = sc;
    shift[c] = fmaf(-mu, sc, beta[c]);
}

// ---------------- fused BN + mean-pool + MLP head: one block per graph ----------------
__global__ __launch_bounds__(256) void k_pool_mlp(
    const float* __restrict__ h2, const float* __restrict__ scale,
    const float* __restrict__ shift, const int* __restrict__ batch,
    const float* __restrict__ Wm1, const float* __restrict__ bm1,
    const float* __restrict__ Wm2, const float* __restrict__ bm2,
    const float* __restrict__ Wm3, const float* __restrict__ bm3,
    float* __restrict__ out)
{
    int g = blockIdx.x, tid = threadIdx.x;
    int lane = tid & 63, wave = tid >> 6;
    __shared__ int sb[2];
    if (tid < 2) {
        int target = g + tid;
        int lo = 0, hi = NN;
        while (lo < hi) {
            int mid = (lo + hi) >> 1;
            if (batch[mid] < target) lo = mid + 1; else hi = mid;
        }
        sb[tid] = lo;
    }
    __syncthreads();
    int s = sb[0], e = sb[1];
    float sc = scale[lane], sh = shift[lane];
    float acc = 0.f;
    for (int n = s + wave; n < e; n += 4)
        acc += fmaf(h2[(size_t)n * 64 + lane], sc, sh);
    __shared__ float red[4][64];
    red[wave][lane] = acc;
    __syncthreads();
    __shared__ float p[64], z1[32], z2[16];
    if (tid < 64) {
        float cnt = (float)(e - s);
        float a = red[0][tid] + red[1][tid] + red[2][tid] + red[3][tid];
        p[tid] = a / fmaxf(cnt, 1.f);
    }
    __syncthreads();
    if (tid < 32) {
        float a = bm1[tid];
        #pragma unroll
        for (int k = 0; k < 64; ++k) a = fmaf(p[k], Wm1[k * 32 + tid], a);
        z1[tid] = fmaxf(a, 0.f);
    }
    __syncthreads();
    if (tid < 16) {
        float a = bm2[tid];
        #pragma unroll
        for (int k = 0; k < 32; ++k) a = fmaf(z1[k], Wm2[k * 16 + tid], a);
        z2[tid] = fmaxf(a, 0.f);
    }
    __syncthreads();
    if (tid == 0) {
        float a = bm3[0];
        #pragma unroll
        for (int k = 0; k < 16; ++k) a = fmaf(z2[k], Wm3[k], a);
        out[g] = a;
    }
}

// ---------------- host launcher ----------------
extern "C" void kernel_launch(void* const* d_in, const int* in_sizes, int n_in,
                              void* d_out, int out_size, void* d_ws, size_t ws_size,
                              hipStream_t stream)
{
    const float* x     = (const float*)d_in[0];
    const float* ea    = (const float*)d_in[1];
    const int*   ei    = (const int*)d_in[2];
    const int*   bat   = (const int*)d_in[3];
    const float* W_in  = (const float*)d_in[4];
    const float* b_in  = (const float*)d_in[5];
    const float* Wl0   = (const float*)d_in[6];
    const float* bl0   = (const float*)d_in[7];
    const float* Wr0   = (const float*)d_in[8];
    const float* br0   = (const float*)d_in[9];
    const float* We0   = (const float*)d_in[10];
    const float* att0  = (const float*)d_in[11];
    const float* bias0 = (const float*)d_in[12];
    const float* g0    = (const float*)d_in[13];
    const float* beta0 = (const float*)d_in[14];
    const float* Wl1   = (const float*)d_in[15];
    const float* bl1   = (const float*)d_in[16];
    const float* Wr1   = (const float*)d_in[17];
    const float* br1   = (const float*)d_in[18];
    const float* We1   = (const float*)d_in[19];
    const float* att1  = (const float*)d_in[20];
    const float* bias1 = (const float*)d_in[21];
    const float* g1    = (const float*)d_in[22];
    const float* beta1 = (const float*)d_in[23];
    const float* Wm1   = (const float*)d_in[24];
    const float* bm1   = (const float*)d_in[25];
    const float* Wm2   = (const float*)d_in[26];
    const float* bm2   = (const float*)d_in[27];
    const float* Wm3   = (const float*)d_in[28];
    const float* bm3   = (const float*)d_in[29];
    const int* src = ei;
    const int* dst = ei + NE;
    float* out = (float*)d_out;

    char* p = (char*)d_ws;
    auto take = [&](size_t nbytes) -> char* {
        char* q = p;
        p += (nbytes + 255) & ~(size_t)255;
        return q;
    };
    // ---- zero zone (one memset) ----
    char* z0 = p;
    int*   hist   = (int*)take((size_t)NN * 4);
    float* bns0   = (float*)take(256 * 4);
    float* bnq0   = (float*)take(256 * 4);
    float* bns1   = (float*)take(64 * 4);
    float* bnq1   = (float*)take(64 * 4);
    size_t zbytes = (size_t)(p - z0);
    // ---- rest of workspace ----
    int*   offs   = (int*)take((size_t)(NN + 1) * 4);
    int*   curs   = (int*)take((size_t)NN * 4);
    int*   bsum   = (int*)take((size_t)SB * 4);
    int*   srcs   = (int*)take((size_t)NE * 4);
    float* eas    = (float*)take((size_t)NE * 16 * 4);
    float* h2     = (float*)take((size_t)NN * 64 * 4);
    float* xl     = (float*)take((size_t)NN * 256 * 4);
    float* xr     = (float*)take((size_t)NN * 256 * 4);
    float* h1     = (float*)take((size_t)NN * 256 * 4);
    float* scale0 = (float*)take(256 * 4);
    float* shift0 = (float*)take(256 * 4);
    float* scale1 = (float*)take(64 * 4);
    float* shift1 = (float*)take(64 * 4);

    hipMemsetAsync(z0, 0, zbytes, stream);

    k_hist<<<(NE + 255) / 256, 256, 0, stream>>>(dst, hist);
    k_scanA<<<SB, 256, 0, stream>>>(hist, offs, bsum);
    k_scanB<<<1, 256, 0, stream>>>(bsum);
    k_scanC<<<SB, 256, 0, stream>>>(hist, bsum, offs, curs);
    k_scatter<<<(NE + 255) / 256, 256, 0, stream>>>(dst, src, ea, curs, srcs, eas);

    constexpr int NPW = 2;
    int attn_blocks = (NN + 4 * NPW - 1) / (4 * NPW);
    int lin_blocks = (NN + 31) / 32;

    // ---- GATv2 layer 0 (input proj fused into dual linear) ----
    k_lin0<<<lin_blocks, 256, 0, stream>>>(
        x, W_in, b_in, Wl0, Wr0, bl0, br0, xl, xr);
    k_attn<true, NPW><<<attn_blocks, 256, 0, stream>>>(
        xl, xr, eas, We0, att0, srcs, offs, bias0, h1);
    k_bn_stats<256><<<256, 256, 0, stream>>>(h1, bns0, bnq0);
    k_bn_finalize<<<1, 256, 0, stream>>>(bns0, bnq0, g0, beta0, scale0, shift0, 256);

    // ---- GATv2 layer 1 (BN0+relu folded into linear input reads) ----
    k_linear2<256, true><<<lin_blocks, 256, 0, stream>>>(
        h1, Wl1, Wr1, bl1, br1, scale0, shift0, xl, xr);
    k_attn<false, NPW><<<attn_blocks, 256, 0, stream>>>(
        xl, xr, eas, We1, att1, srcs, offs, bias1, h2);
    k_bn_stats<64><<<256, 256, 0, stream>>>(h2, bns1, bnq1);
    k_bn_finalize<<<1, 64, 0, stream>>>(bns1, bnq1, g1, beta1, scale1, shift1, 64);

    // ---- fused BN + pool + MLP (graph bounds inline) ----
    k_pool_mlp<<<NG, 256, 0, stream>>>(h2, scale1, shift1, bat,
                                       Wm1, bm1, Wm2, bm2, Wm3, bm3, out);
}